// Round 7
// baseline (479.795 us; speedup 1.0000x reference)
//
#include <hip/hip_runtime.h>
#include <hip/hip_bf16.h>
#include <hip/hip_cooperative_groups.h>

namespace cg = cooperative_groups;

#define NN   5000
#define NP   5008
#define NE   80000
#define HID  128
#define NRBF 64
#define PI_OVER_5 0.6283185307179586f
#define LN_EPS 1e-5f

typedef unsigned short bf16_t;
typedef __attribute__((ext_vector_type(8))) short short8;
typedef __attribute__((ext_vector_type(4))) float floatx4;

__device__ __forceinline__ bf16_t to_bf16(float x){
    union { float f; unsigned int u; } v; v.f = x;
    unsigned int r = v.u + 0x7fffu + ((v.u >> 16) & 1u);
    return (bf16_t)(r >> 16);
}
__device__ __forceinline__ float from_bf16(bf16_t h){
    union { unsigned int u; float f; } v; v.u = ((unsigned int)h) << 16;
    return v.f;
}
__device__ __forceinline__ uint4 pack8(const float* s){
    float4 a = *(const float4*)s;
    float4 b = *(const float4*)(s + 4);
    uint4 o;
    o.x = to_bf16(a.x) | ((unsigned)to_bf16(a.y) << 16);
    o.y = to_bf16(a.z) | ((unsigned)to_bf16(a.w) << 16);
    o.z = to_bf16(b.x) | ((unsigned)to_bf16(b.y) << 16);
    o.w = to_bf16(b.z) | ((unsigned)to_bf16(b.w) << 16);
    return o;
}

struct KP {
    const int *z, *ei;
    const float *ew, *evn, *attr, *emb, *W_emb2, *b_emb2;
    const float *Wd1, *bd1, *Wd2, *bd2, *Wd3, *bd3;
    const float *Wt1, *Wt2, *Wt3, *Ws1, *bs1, *Ws2, *bs2, *ln_g, *ln_b;
    bf16_t *Wcat, *Wtc, *Ws1b, *Ws2b;
    float *bdcat, *embL, *embR;
    int *counts, *offs, *cursor, *elist;
    float2 *meta; float *evn_p;
    bf16_t *f1, *f2, *f3, *accb, *lnb;
    float *out;
};

struct ShEdge {
    bf16_t sB[64 * 72];     // attr tile, 144B row stride
    float  sCut[64];
    int    sZ[64];
};                           // 9728 B
struct ShScan { int s[256]; };
struct ShGat  { float r1[4], r2[4]; };
struct ShNode {
    bf16_t h1s[16 * 280];    // 8960 B
    bf16_t nrms[16 * 392];   // 12544 B  (bf16 to keep union < 22 KB)
};                           // 21504 B
union ShAll { ShEdge edge; ShScan scan; ShGat gat; ShNode node; };

__global__ __launch_bounds__(256, 2) void k_all(KP P)
{
    cg::grid_group grid = cg::this_grid();
    __shared__ __align__(16) ShAll sh;

    const int tid = threadIdx.x;
    const int bid = blockIdx.x;
    const int nblk = gridDim.x;
    const int gthreads = nblk * 256;
    const int gt = bid * 256 + tid;
    const int wv = tid >> 6, lane = tid & 63;
    const int col = lane & 15, q = lane >> 4;

    // ================= P0: weight pack + emb tables + edge count =================
    for (int t = gt; t < 25600; t += gthreads){
        int i8 = t * 8;
        const float* src; bf16_t* dst;
        if (i8 < 24576){
            int j = i8; int tb = j >> 13; int r = j & 8191;
            src = ((tb == 0) ? P.Wd1 : (tb == 1) ? P.Wd2 : P.Wd3) + r; dst = P.Wcat + j;
        } else if (i8 < 24576 + 49152){
            int j = i8 - 24576; int tb = j >> 14; int r = j & 16383;
            src = ((tb == 0) ? P.Wt1 : (tb == 1) ? P.Wt2 : P.Wt3) + r; dst = P.Wtc + j;
        } else if (i8 < 24576 + 49152 + 32768){
            int j = i8 - 73728; src = P.Ws1 + j; dst = P.Ws1b + j;
        } else {
            int j = i8 - 106496; src = P.Ws2 + j; dst = P.Ws2b + j;
        }
        *(uint4*)dst = pack8(src);
        if (t < 384){
            int tb2 = t >> 7, ch2 = t & 127;
            const float* bsrc = (tb2 == 0) ? P.bd1 : ((tb2 == 1) ? P.bd2 : P.bd3);
            P.bdcat[t] = bsrc[ch2];
        }
    }
    for (int t = gt; t < 32768; t += gthreads){
        int type = t >> 8; int rest = t & 255;
        int half = rest >> 7; int h = rest & 127;
        const float* wl = P.W_emb2 + (size_t)h * (2 * HID) + half * HID;
        const float* er = P.emb + type * HID;
        float s = 0.f;
        #pragma unroll 8
        for (int k = 0; k < HID; k++) s += wl[k] * er[k];
        (half ? P.embR : P.embL)[type * HID + h] = s;
    }
    for (int e = gt; e < NE; e += gthreads)
        atomicAdd(&P.counts[P.ei[e]], 1);
    grid.sync();

    // ================= P1: exclusive scan (block 0) =================
    if (bid == 0){
        const int CH = 20;                 // 256*20 = 5120 >= 5000
        int base = tid * CH;
        int loc[CH];
        int lsum = 0;
        #pragma unroll
        for (int u = 0; u < CH; u++){
            int i = base + u;
            int v = (i < NN) ? P.counts[i] : 0;
            loc[u] = lsum; lsum += v;
        }
        sh.scan.s[tid] = lsum;
        __syncthreads();
        for (int d = 1; d < 256; d <<= 1){
            int v = (tid >= d) ? sh.scan.s[tid - d] : 0;
            __syncthreads();
            sh.scan.s[tid] += v;
            __syncthreads();
        }
        int excl = sh.scan.s[tid] - lsum;
        #pragma unroll
        for (int u = 0; u < CH; u++){
            int i = base + u;
            if (i < NN){ int o = excl + loc[u]; P.offs[i] = o; P.cursor[i] = o; }
        }
        if (tid == 255) P.offs[NN] = sh.scan.s[255];
    }
    grid.sync();

    // ================= P2: fill (CSR permute of meta/evn) =================
    for (int e = gt; e < NE; e += gthreads){
        int sN = P.ei[e], dN = P.ei[NE + e];
        int p = atomicAdd(&P.cursor[sN], 1);
        P.elist[p] = e;
        float w = P.ew[e];
        float c = (w < 5.0f) ? 0.5f * (__cosf(w * PI_OVER_5) + 1.0f) : 0.0f;
        P.meta[p] = make_float2(c, __int_as_float(P.z[sN] | (P.z[dN] << 8)));
        P.evn_p[p*3+0] = P.evn[e*3+0];
        P.evn_p[p*3+1] = P.evn[e*3+1];
        P.evn_p[p*3+2] = P.evn[e*3+2];
    }
    grid.sync();

    // ================= P3: edge MFMA -> f1/f2/f3 =================
    for (int tile = bid; tile < NE / 64; tile += nblk){
        const int p0 = tile * 64;
        __syncthreads();   // WAR vs previous tile's readers
        {
            int r = tid >> 2, qt = tid & 3;
            int e = P.elist[p0 + r];
            const float* ar = P.attr + (size_t)e * NRBF + qt * 16;
            uint4 o0 = pack8(ar);
            uint4 o1 = pack8(ar + 8);
            *(uint4*)&sh.edge.sB[r * 72 + qt * 16]     = o0;
            *(uint4*)&sh.edge.sB[r * 72 + qt * 16 + 8] = o1;
        }
        if (tid < 64){
            float2 m = P.meta[p0 + tid];
            sh.edge.sCut[tid] = m.x;
            sh.edge.sZ[tid]   = __float_as_int(m.y);
        }
        __syncthreads();

        floatx4 acc[6][4];
        #pragma unroll
        for (int mt = 0; mt < 6; mt++)
            #pragma unroll
            for (int nt = 0; nt < 4; nt++)
                acc[mt][nt] = (floatx4)(0.f);

        #pragma unroll
        for (int s = 0; s < 2; s++){
            short8 bf[4];
            #pragma unroll
            for (int nt = 0; nt < 4; nt++){
                int r = nt * 16 + col;
                bf[nt] = *(const short8*)&sh.edge.sB[r * 72 + s * 32 + q * 8];
            }
            short8 af[6];
            #pragma unroll
            for (int t = 0; t < 3; t++)
                #pragma unroll
                for (int c = 0; c < 2; c++){
                    int m = t * 128 + wv * 32 + c * 16 + col;
                    af[t * 2 + c] = *(const short8*)(P.Wcat + (size_t)m * NRBF + s * 32 + q * 8);
                }
            #pragma unroll
            for (int mt = 0; mt < 6; mt++)
                #pragma unroll
                for (int nt = 0; nt < 4; nt++)
                    acc[mt][nt] = __builtin_amdgcn_mfma_f32_16x16x32_bf16(
                        af[mt], bf[nt], acc[mt][nt], 0, 0, 0);
        }

        floatx4 be[2], bd[3][2];
        #pragma unroll
        for (int c = 0; c < 2; c++){
            int ch4 = wv * 32 + c * 16 + q * 4;
            be[c] = *(const floatx4*)(P.b_emb2 + ch4);
            #pragma unroll
            for (int t = 0; t < 3; t++)
                bd[t][c] = *(const floatx4*)(P.bdcat + t * 128 + ch4);
        }
        bf16_t* const fs[3] = {P.f1, P.f2, P.f3};
        #pragma unroll
        for (int nt = 0; nt < 4; nt++){
            int e = nt * 16 + col;
            float cut = sh.edge.sCut[e];
            int zp = sh.edge.sZ[e];
            int zs = zp & 255, zd = zp >> 8;
            size_t orow = (size_t)(p0 + e) * HID;
            #pragma unroll
            for (int c = 0; c < 2; c++){
                int ch4 = wv * 32 + c * 16 + q * 4;
                floatx4 L = *(const floatx4*)(P.embL + zs * HID + ch4);
                floatx4 R = *(const floatx4*)(P.embR + zd * HID + ch4);
                floatx4 Cv = (L + R + be[c]) * cut;
                #pragma unroll
                for (int t = 0; t < 3; t++){
                    floatx4 v = (acc[t * 2 + c][nt] + bd[t][c]) * Cv;
                    uint2 pk;
                    pk.x = to_bf16(v[0]) | ((unsigned)to_bf16(v[1]) << 16);
                    pk.y = to_bf16(v[2]) | ((unsigned)to_bf16(v[3]) << 16);
                    *(uint2*)(fs[t] + orow + ch4) = pk;
                }
            }
        }
    }
    grid.sync();

    // ================= P4: gather + LN (2 nodes per pass) =================
    {
        const int half = tid >> 7, h = tid & 127;
        for (int g = bid; g < NN / 2; g += nblk){
            __syncthreads();   // WAR on sh.gat from previous pass
            int n = g * 2 + half;
            const int s = P.offs[n], e_end = P.offs[n + 1];
            float c=0, ax=0, ay=0, az=0, sxx=0, syy=0, szz=0, sxy=0, sxz=0, syz=0;
            for (int idx = s; idx < e_end; idx++){
                float vx = P.evn_p[idx*3+0], vy = P.evn_p[idx*3+1], vz = P.evn_p[idx*3+2];
                float t3 = (vx*vx + vy*vy + vz*vz) * (1.f/3.f);
                float a = from_bf16(P.f1[(size_t)idx * HID + h]);
                float b = from_bf16(P.f2[(size_t)idx * HID + h]);
                float d = from_bf16(P.f3[(size_t)idx * HID + h]);
                c += a;
                ax += b * vx; ay += b * vy; az += b * vz;
                sxx += d * (vx*vx - t3); syy += d * (vy*vy - t3); szz += d * (vz*vz - t3);
                sxy += d * (vx*vy); sxz += d * (vx*vz); syz += d * (vy*vz);
            }
            float tn = 3.f*c*c + 2.f*c*(sxx+syy+szz)
                     + sxx*sxx + syy*syy + szz*szz
                     + 2.f*(sxy*sxy + sxz*sxz + syz*syz)
                     + 2.f*(ax*ax + ay*ay + az*az);
            float s1 = tn, s2 = tn * tn;
            #pragma unroll
            for (int d = 1; d < 64; d <<= 1){
                s1 += __shfl_xor(s1, d);
                s2 += __shfl_xor(s2, d);
            }
            if (lane == 0){ sh.gat.r1[wv] = s1; sh.gat.r2[wv] = s2; }
            __syncthreads();
            float mu  = (sh.gat.r1[half*2] + sh.gat.r1[half*2+1]) * (1.f / HID);
            float var = (sh.gat.r2[half*2] + sh.gat.r2[half*2+1]) * (1.f / HID) - mu * mu;
            float ln = (tn - mu) * rsqrtf(var + LN_EPS) * P.ln_g[h] + P.ln_b[h];
            const size_t base = (size_t)n * HID + h;
            P.lnb[base] = to_bf16(ln);
            P.accb[(size_t)0 * NP * HID + base] = to_bf16(c);
            P.accb[(size_t)1 * NP * HID + base] = to_bf16(ax);
            P.accb[(size_t)2 * NP * HID + base] = to_bf16(ay);
            P.accb[(size_t)3 * NP * HID + base] = to_bf16(az);
            P.accb[(size_t)4 * NP * HID + base] = to_bf16(sxx);
            P.accb[(size_t)5 * NP * HID + base] = to_bf16(syy);
            P.accb[(size_t)6 * NP * HID + base] = to_bf16(szz);
            P.accb[(size_t)7 * NP * HID + base] = to_bf16(sxy);
            P.accb[(size_t)8 * NP * HID + base] = to_bf16(sxz);
            P.accb[(size_t)9 * NP * HID + base] = to_bf16(syz);
        }
    }
    grid.sync();

    // ================= P5: node MLPs + mix + output =================
    for (int g = bid; g < (NN + 15) / 16; g += nblk){
        const int n0 = g * 16;
        // phase 1: h1 = silu(lnb @ Ws1^T + bs1)
        {
            short8 a1[4];
            #pragma unroll
            for (int k = 0; k < 4; k++)
                a1[k] = *(const short8*)(P.lnb + (size_t)(n0 + col) * HID + k * 32 + q * 8);
            floatx4 c1[4];
            #pragma unroll
            for (int nt = 0; nt < 4; nt++) c1[nt] = (floatx4)(0.f);
            #pragma unroll
            for (int nt = 0; nt < 4; nt++){
                int cg = wv * 64 + nt * 16 + col;
                #pragma unroll
                for (int k = 0; k < 4; k++){
                    short8 b = *(const short8*)(P.Ws1b + (size_t)cg * HID + k * 32 + q * 8);
                    c1[nt] = __builtin_amdgcn_mfma_f32_16x16x32_bf16(a1[k], b, c1[nt], 0, 0, 0);
                }
            }
            #pragma unroll
            for (int nt = 0; nt < 4; nt++){
                int cg = wv * 64 + nt * 16 + col;
                float bias = P.bs1[cg];
                #pragma unroll
                for (int r = 0; r < 4; r++){
                    float v = c1[nt][r] + bias;
                    v = v / (1.f + __expf(-v));
                    sh.node.h1s[(q * 4 + r) * 280 + cg] = to_bf16(v);
                }
            }
        }
        __syncthreads();
        // phase 2: norm = silu(h1 @ Ws2^T + bs2)
        {
            short8 a2[8];
            #pragma unroll
            for (int k = 0; k < 8; k++)
                a2[k] = *(const short8*)&sh.node.h1s[col * 280 + k * 32 + q * 8];
            floatx4 c2[6];
            #pragma unroll
            for (int nt = 0; nt < 6; nt++) c2[nt] = (floatx4)(0.f);
            #pragma unroll
            for (int nt = 0; nt < 6; nt++){
                int cg = wv * 96 + nt * 16 + col;
                #pragma unroll
                for (int k = 0; k < 8; k++){
                    short8 b = *(const short8*)(P.Ws2b + (size_t)cg * 256 + k * 32 + q * 8);
                    c2[nt] = __builtin_amdgcn_mfma_f32_16x16x32_bf16(a2[k], b, c2[nt], 0, 0, 0);
                }
            }
            #pragma unroll
            for (int nt = 0; nt < 6; nt++){
                int cg = wv * 96 + nt * 16 + col;
                float bias = P.bs2[cg];
                #pragma unroll
                for (int r = 0; r < 4; r++){
                    float v = c2[nt][r] + bias;
                    v = v / (1.f + __expf(-v));
                    sh.node.nrms[(q * 4 + r) * 392 + cg] = to_bf16(v);
                }
            }
        }
        __syncthreads();
        // phase 3: 10-plane mix GEMM + combine
        floatx4 cm[10][2];
        #pragma unroll
        for (int p = 0; p < 10; p++){
            #pragma unroll
            for (int nt = 0; nt < 2; nt++) cm[p][nt] = (floatx4)(0.f);
        }
        #pragma unroll
        for (int p = 0; p < 10; p++){
            const bf16_t* ap = P.accb + (size_t)p * NP * HID + (size_t)(n0 + col) * HID;
            short8 a3[4];
            #pragma unroll
            for (int k = 0; k < 4; k++)
                a3[k] = *(const short8*)(ap + k * 32 + q * 8);
            int tb = (p == 0) ? 0 : ((p < 4) ? 1 : 2);
            #pragma unroll
            for (int nt = 0; nt < 2; nt++){
                int gg = wv * 32 + nt * 16 + col;
                const bf16_t* wp = P.Wtc + tb * 16384 + (size_t)gg * HID;
                #pragma unroll
                for (int k = 0; k < 4; k++){
                    short8 b = *(const short8*)(wp + k * 32 + q * 8);
                    cm[p][nt] = __builtin_amdgcn_mfma_f32_16x16x32_bf16(a3[k], b, cm[p][nt], 0, 0, 0);
                }
            }
        }
        #pragma unroll
        for (int nt = 0; nt < 2; nt++){
            int gg = wv * 32 + nt * 16 + col;
            #pragma unroll
            for (int r = 0; r < 4; r++){
                int node = q * 4 + r;
                int n = n0 + node;
                if (n < NN){
                    float n0f = from_bf16(sh.node.nrms[node * 392 + gg * 3 + 0]);
                    float n1f = from_bf16(sh.node.nrms[node * 392 + gg * 3 + 1]);
                    float n2f = from_bf16(sh.node.nrms[node * 392 + gg * 3 + 2]);
                    float c   = cm[0][nt][r];
                    float ax  = cm[1][nt][r], ay = cm[2][nt][r], az = cm[3][nt][r];
                    float sxx = cm[4][nt][r], syy= cm[5][nt][r], szz= cm[6][nt][r];
                    float sxy = cm[7][nt][r], sxz= cm[8][nt][r], syz= cm[9][nt][r];
                    float* o = P.out + ((size_t)n * HID + gg) * 9;
                    o[0] = n0f*c + n2f*sxx;   o[1] = n2f*sxy - n1f*az;  o[2] = n2f*sxz + n1f*ay;
                    o[3] = n2f*sxy + n1f*az;  o[4] = n0f*c + n2f*syy;   o[5] = n2f*syz - n1f*ax;
                    o[6] = n2f*sxz - n1f*ay;  o[7] = n2f*syz + n1f*ax;  o[8] = n0f*c + n2f*szz;
                }
            }
        }
        __syncthreads();   // WAR for next group pass (h1s/nrms)
    }
}

// ---------------------------------------------------------------- launch
extern "C" void kernel_launch(void* const* d_in, const int* in_sizes, int n_in,
                              void* d_out, int out_size, void* d_ws, size_t ws_size,
                              hipStream_t stream)
{
    (void)in_sizes; (void)n_in; (void)out_size; (void)ws_size;
    KP kp;
    kp.z      = (const int*)  d_in[0];
    kp.ei     = (const int*)  d_in[1];
    kp.ew     = (const float*)d_in[2];
    kp.evn    = (const float*)d_in[3];
    kp.attr   = (const float*)d_in[4];
    kp.emb    = (const float*)d_in[5];
    kp.W_emb2 = (const float*)d_in[6];
    kp.b_emb2 = (const float*)d_in[7];
    kp.Wd1 = (const float*)d_in[8];  kp.bd1 = (const float*)d_in[9];
    kp.Wd2 = (const float*)d_in[10]; kp.bd2 = (const float*)d_in[11];
    kp.Wd3 = (const float*)d_in[12]; kp.bd3 = (const float*)d_in[13];
    kp.Wt1 = (const float*)d_in[14]; kp.Wt2 = (const float*)d_in[15];
    kp.Wt3 = (const float*)d_in[16];
    kp.Ws1 = (const float*)d_in[17]; kp.bs1 = (const float*)d_in[18];
    kp.Ws2 = (const float*)d_in[19]; kp.bs2 = (const float*)d_in[20];
    kp.ln_g = (const float*)d_in[21]; kp.ln_b = (const float*)d_in[22];
    kp.out = (float*)d_out;

    char* ws = (char*)d_ws;
    size_t o = 0;
    auto take = [&](size_t b)->size_t{ size_t c = o; o += (b + 255) & ~(size_t)255; return c; };
    size_t f1_o  = take((size_t)NE * HID * 2);
    size_t f2_o  = take((size_t)NE * HID * 2);
    size_t f3_o  = take((size_t)NE * HID * 2);
    size_t acc_o = take((size_t)10 * NP * HID * 2);
    size_t ln_of = take((size_t)NP * HID * 2);
    size_t eL_o  = take((size_t)128 * HID * 4);
    size_t eR_o  = take((size_t)128 * HID * 4);
    size_t cnt_o = take((size_t)NN * 4);
    size_t off_o = take((size_t)(NN + 1) * 4);
    size_t cur_o = take((size_t)NN * 4);
    size_t el_o  = take((size_t)NE * 4);
    size_t met_o = take((size_t)NE * 8);
    size_t evp_o = take((size_t)NE * 12);
    size_t wc_o  = take((size_t)384 * 64 * 2);
    size_t wt_o  = take((size_t)3 * 128 * 128 * 2);
    size_t w1_o  = take((size_t)256 * 128 * 2);
    size_t w2_o  = take((size_t)384 * 256 * 2);
    size_t bdc_o = take((size_t)384 * 4);

    kp.f1 = (bf16_t*)(ws + f1_o);
    kp.f2 = (bf16_t*)(ws + f2_o);
    kp.f3 = (bf16_t*)(ws + f3_o);
    kp.accb = (bf16_t*)(ws + acc_o);
    kp.lnb  = (bf16_t*)(ws + ln_of);
    kp.embL = (float*)(ws + eL_o);
    kp.embR = (float*)(ws + eR_o);
    kp.counts = (int*)(ws + cnt_o);
    kp.offs   = (int*)(ws + off_o);
    kp.cursor = (int*)(ws + cur_o);
    kp.elist  = (int*)(ws + el_o);
    kp.meta   = (float2*)(ws + met_o);
    kp.evn_p  = (float*)(ws + evp_o);
    kp.Wcat = (bf16_t*)(ws + wc_o);
    kp.Wtc  = (bf16_t*)(ws + wt_o);
    kp.Ws1b = (bf16_t*)(ws + w1_o);
    kp.Ws2b = (bf16_t*)(ws + w2_o);
    kp.bdcat = (float*)(ws + bdc_o);

    hipMemsetAsync(kp.counts, 0, (size_t)NN * 4, stream);

    // Size the cooperative grid from the runtime's own occupancy answer
    // (pure query — capture-safe, deterministic). Never exceed co-residency.
    int maxb = 0;
    if (hipOccupancyMaxActiveBlocksPerMultiprocessor(
            &maxb, (const void*)k_all, 256, 0) != hipSuccess || maxb < 1)
        maxb = 1;
    int grid = maxb * 256;
    if (grid > 1024) grid = 1024;

    void* args[] = { (void*)&kp };
    hipLaunchCooperativeKernel((const void*)k_all, dim3(grid), dim3(256), args, 0, stream);
}

// Round 8
// 224.482 us; speedup vs baseline: 2.1373x; 2.1373x over previous
//
#include <hip/hip_runtime.h>
#include <hip/hip_bf16.h>

#define NN   5000
#define NP   5008
#define NE   80000
#define HID  128
#define NRBF 64
#define PI_OVER_5 0.6283185307179586f
#define LN_EPS 1e-5f

typedef unsigned short bf16_t;
typedef unsigned int uint_t;
typedef __attribute__((ext_vector_type(8))) short short8;
typedef __attribute__((ext_vector_type(4))) float floatx4;

__device__ __forceinline__ bf16_t to_bf16(float x){
    union { float f; unsigned int u; } v; v.f = x;
    unsigned int r = v.u + 0x7fffu + ((v.u >> 16) & 1u);
    return (bf16_t)(r >> 16);
}
__device__ __forceinline__ float from_bf16(bf16_t h){
    union { unsigned int u; float f; } v; v.u = ((unsigned int)h) << 16;
    return v.f;
}
__device__ __forceinline__ float bf_lo(uint_t u){
    union { unsigned int x; float f; } v; v.x = u << 16; return v.f;
}
__device__ __forceinline__ float bf_hi(uint_t u){
    union { unsigned int x; float f; } v; v.x = u & 0xffff0000u; return v.f;
}
__device__ __forceinline__ uint_t packbf(float a, float b){
    return (uint_t)to_bf16(a) | ((uint_t)to_bf16(b) << 16);
}
__device__ __forceinline__ uint4 pack8(const float* s){
    float4 a = *(const float4*)s;
    float4 b = *(const float4*)(s + 4);
    uint4 o;
    o.x = packbf(a.x, a.y);
    o.y = packbf(a.z, a.w);
    o.z = packbf(b.x, b.y);
    o.w = packbf(b.z, b.w);
    return o;
}

// ---------------------------------------------------------------- prep: weights + emb tables + count
__global__ __launch_bounds__(256) void k_prep(
    const float* __restrict__ Wd1, const float* __restrict__ Wd2, const float* __restrict__ Wd3,
    const float* __restrict__ bd1, const float* __restrict__ bd2, const float* __restrict__ bd3,
    const float* __restrict__ Wt1, const float* __restrict__ Wt2, const float* __restrict__ Wt3,
    const float* __restrict__ Ws1, const float* __restrict__ Ws2,
    const float* __restrict__ W_emb2, const float* __restrict__ emb,
    const int* __restrict__ ei, int* __restrict__ counts,
    bf16_t* __restrict__ Wcat, bf16_t* __restrict__ Wtc,
    bf16_t* __restrict__ Ws1b, bf16_t* __restrict__ Ws2b, float* __restrict__ bdcat,
    float* __restrict__ embL, float* __restrict__ embR)
{
    int b = blockIdx.x, tid = threadIdx.x;
    if (b < 100){
        int t = b * 256 + tid;
        int i8 = t * 8;
        const float* src; bf16_t* dst;
        if (i8 < 24576){
            int j = i8; int tb = j >> 13; int r = j & 8191;
            src = ((tb == 0) ? Wd1 : (tb == 1) ? Wd2 : Wd3) + r; dst = Wcat + j;
        } else if (i8 < 24576 + 49152){
            int j = i8 - 24576; int tb = j >> 14; int r = j & 16383;
            src = ((tb == 0) ? Wt1 : (tb == 1) ? Wt2 : Wt3) + r; dst = Wtc + j;
        } else if (i8 < 24576 + 49152 + 32768){
            int j = i8 - 73728; src = Ws1 + j; dst = Ws1b + j;
        } else {
            int j = i8 - 106496; src = Ws2 + j; dst = Ws2b + j;
        }
        *(uint4*)dst = pack8(src);
        if (t < 384){
            int tb2 = t >> 7, ch2 = t & 127;
            const float* bsrc = (tb2 == 0) ? bd1 : ((tb2 == 1) ? bd2 : bd3);
            bdcat[t] = bsrc[ch2];
        }
    } else if (b < 228){
        int t = b - 100;                 // atom type 0..127
        int half = tid >> 7;             // 0: embL, 1: embR
        int h = tid & 127;
        const float* wl = W_emb2 + (size_t)h * (2 * HID) + half * HID;
        const float* er = emb + t * HID;
        float s = 0.f;
        #pragma unroll 8
        for (int k = 0; k < HID; k++) s += wl[k] * er[k];
        (half ? embR : embL)[t * HID + h] = s;
    } else {
        int e = (b - 228) * 256 + tid;
        if (e < NE) atomicAdd(&counts[ei[e]], 1);
    }
}

// ---------------------------------------------------------------- CSR scan
__global__ __launch_bounds__(1024) void k_scan(
    const int* __restrict__ counts, int* __restrict__ offsets, int* __restrict__ cursor)
{
    __shared__ int s[1024];
    const int t = threadIdx.x;
    const int CH = 5;
    int base = t * CH;
    int loc[CH];
    int lsum = 0;
    #pragma unroll
    for (int u = 0; u < CH; u++){
        int i = base + u;
        int v = (i < NN) ? counts[i] : 0;
        loc[u] = lsum;
        lsum += v;
    }
    s[t] = lsum;
    __syncthreads();
    for (int d = 1; d < 1024; d <<= 1){
        int v = (t >= d) ? s[t - d] : 0;
        __syncthreads();
        s[t] += v;
        __syncthreads();
    }
    int excl = s[t] - lsum;
    #pragma unroll
    for (int u = 0; u < CH; u++){
        int i = base + u;
        if (i < NN){ int o = excl + loc[u]; offsets[i] = o; cursor[i] = o; }
    }
    if (t == 1023) offsets[NN] = s[1023];
}

__global__ void k_fill(const int* __restrict__ ei, const int* __restrict__ z,
                       const float* __restrict__ ew, const float* __restrict__ evn,
                       int* __restrict__ cursor, int* __restrict__ elist,
                       float2* __restrict__ meta, float* __restrict__ evn_p){
    int e = blockIdx.x * 256 + threadIdx.x;
    if (e < NE){
        int sN = ei[e], dN = ei[NE + e];
        int p = atomicAdd(&cursor[sN], 1);
        elist[p] = e;
        float w = ew[e];
        float c = (w < 5.0f) ? 0.5f * (__cosf(w * PI_OVER_5) + 1.0f) : 0.0f;
        meta[p] = make_float2(c, __int_as_float(z[sN] | (z[dN] << 8)));
        evn_p[p*3+0] = evn[e*3+0];
        evn_p[p*3+1] = evn[e*3+1];
        evn_p[p*3+2] = evn[e*3+2];
    }
}

// ---------------------------------------------------------------- edge MFMA (r3-proven)
__global__ __launch_bounds__(256) void k_edge(
    const float* __restrict__ attr, const int* __restrict__ elist,
    const float2* __restrict__ meta,
    const bf16_t* __restrict__ Wcat, const float* __restrict__ bdcat,
    const float* __restrict__ embL, const float* __restrict__ embR,
    const float* __restrict__ b_emb2,
    bf16_t* __restrict__ f1, bf16_t* __restrict__ f2, bf16_t* __restrict__ f3)
{
    __shared__ __align__(16) bf16_t sB[64 * 72];   // 144B row stride
    __shared__ float sCut[64];
    __shared__ int   sZ[64];

    const int tid = threadIdx.x;
    const int p0  = blockIdx.x * 64;

    {
        int r = tid >> 2, qt = tid & 3;
        int e = elist[p0 + r];
        const float* ar = attr + (size_t)e * NRBF + qt * 16;
        uint4 o0 = pack8(ar);
        uint4 o1 = pack8(ar + 8);
        *(uint4*)&sB[r * 72 + qt * 16]     = o0;
        *(uint4*)&sB[r * 72 + qt * 16 + 8] = o1;
    }
    if (tid < 64){
        float2 m = meta[p0 + tid];
        sCut[tid] = m.x;
        sZ[tid]   = __float_as_int(m.y);
    }
    __syncthreads();

    const int wv = tid >> 6, lane = tid & 63;
    const int col = lane & 15, q = lane >> 4;

    floatx4 acc[6][4];
    #pragma unroll
    for (int mt = 0; mt < 6; mt++)
        #pragma unroll
        for (int nt = 0; nt < 4; nt++)
            acc[mt][nt] = (floatx4)(0.f);

    #pragma unroll
    for (int s = 0; s < 2; s++){
        short8 bf[4];
        #pragma unroll
        for (int nt = 0; nt < 4; nt++){
            int r = nt * 16 + col;
            bf[nt] = *(const short8*)&sB[r * 72 + s * 32 + q * 8];
        }
        short8 af[6];
        #pragma unroll
        for (int t = 0; t < 3; t++)
            #pragma unroll
            for (int c = 0; c < 2; c++){
                int m = t * 128 + wv * 32 + c * 16 + col;
                af[t * 2 + c] = *(const short8*)(Wcat + (size_t)m * NRBF + s * 32 + q * 8);
            }
        #pragma unroll
        for (int mt = 0; mt < 6; mt++)
            #pragma unroll
            for (int nt = 0; nt < 4; nt++)
                acc[mt][nt] = __builtin_amdgcn_mfma_f32_16x16x32_bf16(
                    af[mt], bf[nt], acc[mt][nt], 0, 0, 0);
    }

    floatx4 be[2], bd[3][2];
    #pragma unroll
    for (int c = 0; c < 2; c++){
        int ch4 = wv * 32 + c * 16 + q * 4;
        be[c] = *(const floatx4*)(b_emb2 + ch4);
        #pragma unroll
        for (int t = 0; t < 3; t++)
            bd[t][c] = *(const floatx4*)(bdcat + t * 128 + ch4);
    }
    bf16_t* const fs[3] = {f1, f2, f3};
    #pragma unroll
    for (int nt = 0; nt < 4; nt++){
        int e = nt * 16 + col;
        float cut = sCut[e];
        int zp = sZ[e];
        int zs = zp & 255, zd = zp >> 8;
        size_t orow = (size_t)(p0 + e) * HID;
        #pragma unroll
        for (int c = 0; c < 2; c++){
            int ch4 = wv * 32 + c * 16 + q * 4;
            floatx4 L = *(const floatx4*)(embL + zs * HID + ch4);
            floatx4 R = *(const floatx4*)(embR + zd * HID + ch4);
            floatx4 Cv = (L + R + be[c]) * cut;
            #pragma unroll
            for (int t = 0; t < 3; t++){
                floatx4 v = (acc[t * 2 + c][nt] + bd[t][c]) * Cv;
                uint2 pk;
                pk.x = packbf(v[0], v[1]);
                pk.y = packbf(v[2], v[3]);
                *(uint2*)(fs[t] + orow + ch4) = pk;
            }
        }
    }
}

// ---------------------------------------------------------------- gather + LN: wave per node
// 4 waves/block = 4 nodes; lane holds channels {2*lane, 2*lane+1} via packed uint loads.
__global__ __launch_bounds__(256) void k_gather(
    const int* __restrict__ offs, const float* __restrict__ evn_p,
    const bf16_t* __restrict__ f1, const bf16_t* __restrict__ f2, const bf16_t* __restrict__ f3,
    const float* __restrict__ ln_g, const float* __restrict__ ln_b,
    bf16_t* __restrict__ accb, bf16_t* __restrict__ lnb)
{
    const int tid = threadIdx.x;
    const int wv = tid >> 6, lane = tid & 63;
    const int n = blockIdx.x * 4 + wv;
    const int s = offs[n], e_end = offs[n + 1];

    const uint_t* F1 = (const uint_t*)f1;
    const uint_t* F2 = (const uint_t*)f2;
    const uint_t* F3 = (const uint_t*)f3;

    float c0=0,c1=0, ax0=0,ax1=0, ay0=0,ay1=0, az0=0,az1=0;
    float sxx0=0,sxx1=0, syy0=0,syy1=0, szz0=0,szz1=0;
    float sxy0=0,sxy1=0, sxz0=0,sxz1=0, syz0=0,syz1=0;

    for (int idx = s; idx < e_end; idx++){
        size_t row = (size_t)idx * 64 + lane;
        uint_t u1 = F1[row];
        uint_t u2 = F2[row];
        uint_t u3 = F3[row];
        float vx = evn_p[idx*3+0], vy = evn_p[idx*3+1], vz = evn_p[idx*3+2];
        float xx = vx*vx, yy = vy*vy, zz = vz*vz;
        float t3 = (xx + yy + zz) * (1.f/3.f);
        float gxx = xx - t3, gyy = yy - t3, gzz = zz - t3;
        float gxy = vx*vy, gxz = vx*vz, gyz = vy*vz;
        float a0 = bf_lo(u1), a1 = bf_hi(u1);
        float b0 = bf_lo(u2), b1 = bf_hi(u2);
        float d0 = bf_lo(u3), d1 = bf_hi(u3);
        c0 += a0;            c1 += a1;
        ax0 += b0 * vx;      ax1 += b1 * vx;
        ay0 += b0 * vy;      ay1 += b1 * vy;
        az0 += b0 * vz;      az1 += b1 * vz;
        sxx0 += d0 * gxx;    sxx1 += d1 * gxx;
        syy0 += d0 * gyy;    syy1 += d1 * gyy;
        szz0 += d0 * gzz;    szz1 += d1 * gzz;
        sxy0 += d0 * gxy;    sxy1 += d1 * gxy;
        sxz0 += d0 * gxz;    sxz1 += d1 * gxz;
        syz0 += d0 * gyz;    syz1 += d1 * gyz;
    }

    float tn0 = 3.f*c0*c0 + 2.f*c0*(sxx0+syy0+szz0)
              + sxx0*sxx0 + syy0*syy0 + szz0*szz0
              + 2.f*(sxy0*sxy0 + sxz0*sxz0 + syz0*syz0)
              + 2.f*(ax0*ax0 + ay0*ay0 + az0*az0);
    float tn1 = 3.f*c1*c1 + 2.f*c1*(sxx1+syy1+szz1)
              + sxx1*sxx1 + syy1*syy1 + szz1*szz1
              + 2.f*(sxy1*sxy1 + sxz1*sxz1 + syz1*syz1)
              + 2.f*(ax1*ax1 + ay1*ay1 + az1*az1);

    float s1 = tn0 + tn1, s2 = tn0*tn0 + tn1*tn1;
    #pragma unroll
    for (int d = 1; d < 64; d <<= 1){
        s1 += __shfl_xor(s1, d);
        s2 += __shfl_xor(s2, d);
    }
    float mu  = s1 * (1.f / HID);
    float var = s2 * (1.f / HID) - mu * mu;
    float rs  = rsqrtf(var + LN_EPS);
    float2 g2 = *(const float2*)(ln_g + lane * 2);
    float2 b2 = *(const float2*)(ln_b + lane * 2);
    float ln0 = (tn0 - mu) * rs * g2.x + b2.x;
    float ln1 = (tn1 - mu) * rs * g2.y + b2.y;

    const size_t nrow = (size_t)n * 64 + lane;
    uint_t* LN = (uint_t*)lnb;
    uint_t* AC = (uint_t*)accb;
    LN[nrow] = packbf(ln0, ln1);
    const size_t PS = (size_t)NP * 64;
    AC[0*PS + nrow] = packbf(c0, c1);
    AC[1*PS + nrow] = packbf(ax0, ax1);
    AC[2*PS + nrow] = packbf(ay0, ay1);
    AC[3*PS + nrow] = packbf(az0, az1);
    AC[4*PS + nrow] = packbf(sxx0, sxx1);
    AC[5*PS + nrow] = packbf(syy0, syy1);
    AC[6*PS + nrow] = packbf(szz0, szz1);
    AC[7*PS + nrow] = packbf(sxy0, sxy1);
    AC[8*PS + nrow] = packbf(sxz0, sxz1);
    AC[9*PS + nrow] = packbf(syz0, syz1);
}

// ---------------------------------------------------------------- fused node kernel (r3-proven)
__global__ __launch_bounds__(256) void k_node(
    const bf16_t* __restrict__ lnb, const bf16_t* __restrict__ accb,
    const bf16_t* __restrict__ Ws1b, const float* __restrict__ bs1,
    const bf16_t* __restrict__ Ws2b, const float* __restrict__ bs2,
    const bf16_t* __restrict__ Wtc,
    float* __restrict__ out)
{
    __shared__ __align__(16) bf16_t h1s[16 * 280];
    __shared__ float nrms[16 * 392];

    const int tid = threadIdx.x;
    const int wv = tid >> 6, lane = tid & 63;
    const int col = lane & 15, q = lane >> 4;
    const int n0 = blockIdx.x * 16;

    {
        short8 a1[4];
        #pragma unroll
        for (int k = 0; k < 4; k++)
            a1[k] = *(const short8*)(lnb + (size_t)(n0 + col) * HID + k * 32 + q * 8);
        floatx4 c1[4];
        #pragma unroll
        for (int nt = 0; nt < 4; nt++) c1[nt] = (floatx4)(0.f);
        #pragma unroll
        for (int nt = 0; nt < 4; nt++){
            int cg = wv * 64 + nt * 16 + col;
            #pragma unroll
            for (int k = 0; k < 4; k++){
                short8 b = *(const short8*)(Ws1b + (size_t)cg * HID + k * 32 + q * 8);
                c1[nt] = __builtin_amdgcn_mfma_f32_16x16x32_bf16(a1[k], b, c1[nt], 0, 0, 0);
            }
        }
        #pragma unroll
        for (int nt = 0; nt < 4; nt++){
            int cg = wv * 64 + nt * 16 + col;
            float bias = bs1[cg];
            #pragma unroll
            for (int r = 0; r < 4; r++){
                float v = c1[nt][r] + bias;
                v = v / (1.f + __expf(-v));
                h1s[(q * 4 + r) * 280 + cg] = to_bf16(v);
            }
        }
    }
    __syncthreads();

    {
        short8 a2[8];
        #pragma unroll
        for (int k = 0; k < 8; k++)
            a2[k] = *(const short8*)&h1s[col * 280 + k * 32 + q * 8];
        floatx4 c2[6];
        #pragma unroll
        for (int nt = 0; nt < 6; nt++) c2[nt] = (floatx4)(0.f);
        #pragma unroll
        for (int nt = 0; nt < 6; nt++){
            int cg = wv * 96 + nt * 16 + col;
            #pragma unroll
            for (int k = 0; k < 8; k++){
                short8 b = *(const short8*)(Ws2b + (size_t)cg * 256 + k * 32 + q * 8);
                c2[nt] = __builtin_amdgcn_mfma_f32_16x16x32_bf16(a2[k], b, c2[nt], 0, 0, 0);
            }
        }
        #pragma unroll
        for (int nt = 0; nt < 6; nt++){
            int cg = wv * 96 + nt * 16 + col;
            float bias = bs2[cg];
            #pragma unroll
            for (int r = 0; r < 4; r++){
                float v = c2[nt][r] + bias;
                v = v / (1.f + __expf(-v));
                nrms[(q * 4 + r) * 392 + cg] = v;
            }
        }
    }
    __syncthreads();

    floatx4 cm[10][2];
    #pragma unroll
    for (int p = 0; p < 10; p++){
        #pragma unroll
        for (int nt = 0; nt < 2; nt++) cm[p][nt] = (floatx4)(0.f);
    }
    #pragma unroll
    for (int p = 0; p < 10; p++){
        const bf16_t* ap = accb + (size_t)p * NP * HID + (size_t)(n0 + col) * HID;
        short8 a3[4];
        #pragma unroll
        for (int k = 0; k < 4; k++)
            a3[k] = *(const short8*)(ap + k * 32 + q * 8);
        int tb = (p == 0) ? 0 : ((p < 4) ? 1 : 2);
        #pragma unroll
        for (int nt = 0; nt < 2; nt++){
            int g = wv * 32 + nt * 16 + col;
            const bf16_t* wp = Wtc + tb * 16384 + (size_t)g * HID;
            #pragma unroll
            for (int k = 0; k < 4; k++){
                short8 b = *(const short8*)(wp + k * 32 + q * 8);
                cm[p][nt] = __builtin_amdgcn_mfma_f32_16x16x32_bf16(a3[k], b, cm[p][nt], 0, 0, 0);
            }
        }
    }
    #pragma unroll
    for (int nt = 0; nt < 2; nt++){
        int g = wv * 32 + nt * 16 + col;
        #pragma unroll
        for (int r = 0; r < 4; r++){
            int node = q * 4 + r;
            int n = n0 + node;
            if (n < NN){
                float n0f = nrms[node * 392 + g * 3 + 0];
                float n1f = nrms[node * 392 + g * 3 + 1];
                float n2f = nrms[node * 392 + g * 3 + 2];
                float c   = cm[0][nt][r];
                float ax  = cm[1][nt][r], ay = cm[2][nt][r], az = cm[3][nt][r];
                float sxx = cm[4][nt][r], syy= cm[5][nt][r], szz= cm[6][nt][r];
                float sxy = cm[7][nt][r], sxz= cm[8][nt][r], syz= cm[9][nt][r];
                float* o = out + ((size_t)n * HID + g) * 9;
                o[0] = n0f*c + n2f*sxx;   o[1] = n2f*sxy - n1f*az;  o[2] = n2f*sxz + n1f*ay;
                o[3] = n2f*sxy + n1f*az;  o[4] = n0f*c + n2f*syy;   o[5] = n2f*syz - n1f*ax;
                o[6] = n2f*sxz - n1f*ay;  o[7] = n2f*syz + n1f*ax;  o[8] = n0f*c + n2f*szz;
            }
        }
    }
}

// ---------------------------------------------------------------- launch
extern "C" void kernel_launch(void* const* d_in, const int* in_sizes, int n_in,
                              void* d_out, int out_size, void* d_ws, size_t ws_size,
                              hipStream_t stream)
{
    (void)in_sizes; (void)n_in; (void)out_size; (void)ws_size;
    const int*   z      = (const int*)  d_in[0];
    const int*   ei     = (const int*)  d_in[1];
    const float* ew     = (const float*)d_in[2];
    const float* evn    = (const float*)d_in[3];
    const float* attr   = (const float*)d_in[4];
    const float* emb    = (const float*)d_in[5];
    const float* W_emb2 = (const float*)d_in[6];
    const float* b_emb2 = (const float*)d_in[7];
    const float* Wd1 = (const float*)d_in[8];  const float* bd1 = (const float*)d_in[9];
    const float* Wd2 = (const float*)d_in[10]; const float* bd2 = (const float*)d_in[11];
    const float* Wd3 = (const float*)d_in[12]; const float* bd3 = (const float*)d_in[13];
    const float* Wt1 = (const float*)d_in[14]; const float* Wt2 = (const float*)d_in[15];
    const float* Wt3 = (const float*)d_in[16];
    const float* Ws1 = (const float*)d_in[17]; const float* bs1 = (const float*)d_in[18];
    const float* Ws2 = (const float*)d_in[19]; const float* bs2 = (const float*)d_in[20];
    const float* ln_g = (const float*)d_in[21]; const float* ln_b = (const float*)d_in[22];
    float* out = (float*)d_out;

    char* ws = (char*)d_ws;
    size_t o = 0;
    auto take = [&](size_t b)->size_t{ size_t c = o; o += (b + 255) & ~(size_t)255; return c; };
    size_t f1_o  = take((size_t)NE * HID * 2);
    size_t f2_o  = take((size_t)NE * HID * 2);
    size_t f3_o  = take((size_t)NE * HID * 2);
    size_t acc_o = take((size_t)10 * NP * HID * 2);
    size_t ln_of = take((size_t)NP * HID * 2);
    size_t eL_o  = take((size_t)128 * HID * 4);
    size_t eR_o  = take((size_t)128 * HID * 4);
    size_t cnt_o = take((size_t)NN * 4);
    size_t off_o = take((size_t)(NN + 1) * 4);
    size_t cur_o = take((size_t)NN * 4);
    size_t el_o  = take((size_t)NE * 4);
    size_t met_o = take((size_t)NE * 8);
    size_t evp_o = take((size_t)NE * 12);
    size_t wc_o  = take((size_t)384 * 64 * 2);
    size_t wt_o  = take((size_t)3 * 128 * 128 * 2);
    size_t w1_o  = take((size_t)256 * 128 * 2);
    size_t w2_o  = take((size_t)384 * 256 * 2);
    size_t bdc_o = take((size_t)384 * 4);

    bf16_t* f1 = (bf16_t*)(ws + f1_o);
    bf16_t* f2 = (bf16_t*)(ws + f2_o);
    bf16_t* f3 = (bf16_t*)(ws + f3_o);
    bf16_t* accb = (bf16_t*)(ws + acc_o);
    bf16_t* lnb  = (bf16_t*)(ws + ln_of);
    float* embL = (float*)(ws + eL_o);
    float* embR = (float*)(ws + eR_o);
    int* counts = (int*)(ws + cnt_o);
    int* offs   = (int*)(ws + off_o);
    int* cursor = (int*)(ws + cur_o);
    int* elist  = (int*)(ws + el_o);
    float2* meta = (float2*)(ws + met_o);
    float* evn_p = (float*)(ws + evp_o);
    bf16_t* Wcat = (bf16_t*)(ws + wc_o);
    bf16_t* Wtc  = (bf16_t*)(ws + wt_o);
    bf16_t* Ws1b = (bf16_t*)(ws + w1_o);
    bf16_t* Ws2b = (bf16_t*)(ws + w2_o);
    float* bdcat = (float*)(ws + bdc_o);

    hipMemsetAsync(counts, 0, (size_t)NN * 4, stream);

    k_prep <<<228 + (NE + 255) / 256, 256, 0, stream>>>(
        Wd1, Wd2, Wd3, bd1, bd2, bd3, Wt1, Wt2, Wt3, Ws1, Ws2, W_emb2, emb,
        ei, counts, Wcat, Wtc, Ws1b, Ws2b, bdcat, embL, embR);
    k_scan <<<1, 1024, 0, stream>>>(counts, offs, cursor);
    k_fill <<<(NE + 255) / 256, 256, 0, stream>>>(ei, z, ew, evn, cursor, elist, meta, evn_p);
    k_edge <<<NE / 64, 256, 0, stream>>>(attr, elist, meta, Wcat, bdcat,
                                         embL, embR, b_emb2, f1, f2, f3);
    k_gather<<<NN / 4, 256, 0, stream>>>(offs, evn_p, f1, f2, f3, ln_g, ln_b, accb, lnb);
    k_node <<<(NN + 15) / 16, 256, 0, stream>>>(lnb, accb, Ws1b, bs1, Ws2b, bs2, Wtc, out);
}

// Round 9
// 218.581 us; speedup vs baseline: 2.1950x; 1.0270x over previous
//
#include <hip/hip_runtime.h>
#include <hip/hip_bf16.h>

#define NN   5000
#define NP   5008
#define NE   80000
#define HID  128
#define NRBF 64
#define MAXD 64           // per-node bucket capacity (Poisson(16): P(deg>64) ~ 0)
#define PI_OVER_5 0.6283185307179586f
#define LN_EPS 1e-5f

typedef unsigned short bf16_t;
typedef unsigned int uint_t;
typedef __attribute__((ext_vector_type(8))) short short8;
typedef __attribute__((ext_vector_type(4))) float floatx4;

__device__ __forceinline__ bf16_t to_bf16(float x){
    union { float f; unsigned int u; } v; v.f = x;
    unsigned int r = v.u + 0x7fffu + ((v.u >> 16) & 1u);
    return (bf16_t)(r >> 16);
}
__device__ __forceinline__ float bf_lo(uint_t u){
    union { unsigned int x; float f; } v; v.x = u << 16; return v.f;
}
__device__ __forceinline__ float bf_hi(uint_t u){
    union { unsigned int x; float f; } v; v.x = u & 0xffff0000u; return v.f;
}
__device__ __forceinline__ uint_t packbf(float a, float b){
    return (uint_t)to_bf16(a) | ((uint_t)to_bf16(b) << 16);
}
__device__ __forceinline__ uint4 pack8(const float* s){
    float4 a = *(const float4*)s;
    float4 b = *(const float4*)(s + 4);
    uint4 o;
    o.x = packbf(a.x, a.y);
    o.y = packbf(a.z, a.w);
    o.z = packbf(b.x, b.y);
    o.w = packbf(b.z, b.w);
    return o;
}

// ---------------------------------------------------------------- prep:
// blocks 0..99   : pack Wd/Wt/Ws1/Ws2 -> bf16
// blocks 100..227: embL/embR tables
// blocks 228..   : edge pass: meta2[e]=(cut,zpack), evn4[e], bucket append
__global__ __launch_bounds__(256) void k_prep(
    const float* __restrict__ Wd1, const float* __restrict__ Wd2, const float* __restrict__ Wd3,
    const float* __restrict__ bd1, const float* __restrict__ bd2, const float* __restrict__ bd3,
    const float* __restrict__ Wt1, const float* __restrict__ Wt2, const float* __restrict__ Wt3,
    const float* __restrict__ Ws1, const float* __restrict__ Ws2,
    const float* __restrict__ W_emb2, const float* __restrict__ emb,
    const int* __restrict__ ei, const int* __restrict__ z,
    const float* __restrict__ ew, const float* __restrict__ evn,
    int* __restrict__ cnt, int* __restrict__ bucket,
    float2* __restrict__ meta2, float4* __restrict__ evn4,
    bf16_t* __restrict__ Wcat, bf16_t* __restrict__ Wtc,
    bf16_t* __restrict__ Ws1b, bf16_t* __restrict__ Ws2b, float* __restrict__ bdcat,
    float* __restrict__ embL, float* __restrict__ embR)
{
    int b = blockIdx.x, tid = threadIdx.x;
    if (b < 100){
        int t = b * 256 + tid;
        int i8 = t * 8;
        const float* src; bf16_t* dst;
        if (i8 < 24576){
            int j = i8; int tb = j >> 13; int r = j & 8191;
            src = ((tb == 0) ? Wd1 : (tb == 1) ? Wd2 : Wd3) + r; dst = Wcat + j;
        } else if (i8 < 24576 + 49152){
            int j = i8 - 24576; int tb = j >> 14; int r = j & 16383;
            src = ((tb == 0) ? Wt1 : (tb == 1) ? Wt2 : Wt3) + r; dst = Wtc + j;
        } else if (i8 < 24576 + 49152 + 32768){
            int j = i8 - 73728; src = Ws1 + j; dst = Ws1b + j;
        } else {
            int j = i8 - 106496; src = Ws2 + j; dst = Ws2b + j;
        }
        *(uint4*)dst = pack8(src);
        if (t < 384){
            int tb2 = t >> 7, ch2 = t & 127;
            const float* bsrc = (tb2 == 0) ? bd1 : ((tb2 == 1) ? bd2 : bd3);
            bdcat[t] = bsrc[ch2];
        }
    } else if (b < 228){
        int t = b - 100;                 // atom type 0..127
        int half = tid >> 7;             // 0: embL, 1: embR
        int h = tid & 127;
        const float* wl = W_emb2 + (size_t)h * (2 * HID) + half * HID;
        const float* er = emb + t * HID;
        float s = 0.f;
        #pragma unroll 8
        for (int k = 0; k < HID; k++) s += wl[k] * er[k];
        (half ? embR : embL)[t * HID + h] = s;
    } else {
        int e = (b - 228) * 256 + tid;
        if (e < NE){
            int sN = ei[e], dN = ei[NE + e];
            float w = ew[e];
            float c = (w < 5.0f) ? 0.5f * (__cosf(w * PI_OVER_5) + 1.0f) : 0.0f;
            meta2[e] = make_float2(c, __int_as_float(z[sN] | (z[dN] << 8)));
            evn4[e] = make_float4(evn[e*3+0], evn[e*3+1], evn[e*3+2], 0.f);
            int p = atomicAdd(&cnt[sN], 1);
            if (p < MAXD) bucket[sN * MAXD + p] = e;
        }
    }
}

// ---------------------------------------------------------------- edge MFMA (natural order, streaming)
__global__ __launch_bounds__(256) void k_edge(
    const float* __restrict__ attr, const float2* __restrict__ meta2,
    const bf16_t* __restrict__ Wcat, const float* __restrict__ bdcat,
    const float* __restrict__ embL, const float* __restrict__ embR,
    const float* __restrict__ b_emb2,
    bf16_t* __restrict__ f1, bf16_t* __restrict__ f2, bf16_t* __restrict__ f3)
{
    __shared__ __align__(16) bf16_t sB[64 * 72];   // 144B row stride
    __shared__ float sCut[64];
    __shared__ int   sZ[64];

    const int tid = threadIdx.x;
    const int p0  = blockIdx.x * 64;

    {
        int r = tid >> 2, qt = tid & 3;
        const float* ar = attr + (size_t)(p0 + r) * NRBF + qt * 16;
        uint4 o0 = pack8(ar);
        uint4 o1 = pack8(ar + 8);
        *(uint4*)&sB[r * 72 + qt * 16]     = o0;
        *(uint4*)&sB[r * 72 + qt * 16 + 8] = o1;
    }
    if (tid < 64){
        float2 m = meta2[p0 + tid];
        sCut[tid] = m.x;
        sZ[tid]   = __float_as_int(m.y);
    }
    __syncthreads();

    const int wv = tid >> 6, lane = tid & 63;
    const int col = lane & 15, q = lane >> 4;

    floatx4 acc[6][4];
    #pragma unroll
    for (int mt = 0; mt < 6; mt++)
        #pragma unroll
        for (int nt = 0; nt < 4; nt++)
            acc[mt][nt] = (floatx4)(0.f);

    #pragma unroll
    for (int s = 0; s < 2; s++){
        short8 bf[4];
        #pragma unroll
        for (int nt = 0; nt < 4; nt++){
            int r = nt * 16 + col;
            bf[nt] = *(const short8*)&sB[r * 72 + s * 32 + q * 8];
        }
        short8 af[6];
        #pragma unroll
        for (int t = 0; t < 3; t++)
            #pragma unroll
            for (int c = 0; c < 2; c++){
                int m = t * 128 + wv * 32 + c * 16 + col;
                af[t * 2 + c] = *(const short8*)(Wcat + (size_t)m * NRBF + s * 32 + q * 8);
            }
        #pragma unroll
        for (int mt = 0; mt < 6; mt++)
            #pragma unroll
            for (int nt = 0; nt < 4; nt++)
                acc[mt][nt] = __builtin_amdgcn_mfma_f32_16x16x32_bf16(
                    af[mt], bf[nt], acc[mt][nt], 0, 0, 0);
    }

    floatx4 be[2], bd[3][2];
    #pragma unroll
    for (int c = 0; c < 2; c++){
        int ch4 = wv * 32 + c * 16 + q * 4;
        be[c] = *(const floatx4*)(b_emb2 + ch4);
        #pragma unroll
        for (int t = 0; t < 3; t++)
            bd[t][c] = *(const floatx4*)(bdcat + t * 128 + ch4);
    }
    bf16_t* const fs[3] = {f1, f2, f3};
    #pragma unroll
    for (int nt = 0; nt < 4; nt++){
        int e = nt * 16 + col;
        float cut = sCut[e];
        int zp = sZ[e];
        int zs = zp & 255, zd = zp >> 8;
        size_t orow = (size_t)(p0 + e) * HID;
        #pragma unroll
        for (int c = 0; c < 2; c++){
            int ch4 = wv * 32 + c * 16 + q * 4;
            floatx4 L = *(const floatx4*)(embL + zs * HID + ch4);
            floatx4 R = *(const floatx4*)(embR + zd * HID + ch4);
            floatx4 Cv = (L + R + be[c]) * cut;
            #pragma unroll
            for (int t = 0; t < 3; t++){
                floatx4 v = (acc[t * 2 + c][nt] + bd[t][c]) * Cv;
                uint2 pk;
                pk.x = packbf(v[0], v[1]);
                pk.y = packbf(v[2], v[3]);
                *(uint2*)(fs[t] + orow + ch4) = pk;
            }
        }
    }
}

// ---------------------------------------------------------------- gather + LN: wave per node, bucket lists
__global__ __launch_bounds__(256) void k_gather(
    const int* __restrict__ cnt, const int* __restrict__ bucket,
    const float4* __restrict__ evn4,
    const bf16_t* __restrict__ f1, const bf16_t* __restrict__ f2, const bf16_t* __restrict__ f3,
    const float* __restrict__ ln_g, const float* __restrict__ ln_b,
    bf16_t* __restrict__ accb, bf16_t* __restrict__ lnb)
{
    const int tid = threadIdx.x;
    const int wv = tid >> 6, lane = tid & 63;
    const int n = blockIdx.x * 4 + wv;
    int deg = cnt[n]; if (deg > MAXD) deg = MAXD;
    const int* bk = bucket + n * MAXD;

    const uint_t* F1 = (const uint_t*)f1;
    const uint_t* F2 = (const uint_t*)f2;
    const uint_t* F3 = (const uint_t*)f3;

    float c0=0,c1=0, ax0=0,ax1=0, ay0=0,ay1=0, az0=0,az1=0;
    float sxx0=0,sxx1=0, syy0=0,syy1=0, szz0=0,szz1=0;
    float sxy0=0,sxy1=0, sxz0=0,sxz1=0, syz0=0,syz1=0;

    for (int idx = 0; idx < deg; idx++){
        int e = bk[idx];
        size_t row = (size_t)e * 64 + lane;
        uint_t u1 = F1[row];
        uint_t u2 = F2[row];
        uint_t u3 = F3[row];
        float4 v4 = evn4[e];
        float vx = v4.x, vy = v4.y, vz = v4.z;
        float xx = vx*vx, yy = vy*vy, zz = vz*vz;
        float t3 = (xx + yy + zz) * (1.f/3.f);
        float gxx = xx - t3, gyy = yy - t3, gzz = zz - t3;
        float gxy = vx*vy, gxz = vx*vz, gyz = vy*vz;
        float a0 = bf_lo(u1), a1 = bf_hi(u1);
        float b0 = bf_lo(u2), b1 = bf_hi(u2);
        float d0 = bf_lo(u3), d1 = bf_hi(u3);
        c0 += a0;            c1 += a1;
        ax0 += b0 * vx;      ax1 += b1 * vx;
        ay0 += b0 * vy;      ay1 += b1 * vy;
        az0 += b0 * vz;      az1 += b1 * vz;
        sxx0 += d0 * gxx;    sxx1 += d1 * gxx;
        syy0 += d0 * gyy;    syy1 += d1 * gyy;
        szz0 += d0 * gzz;    szz1 += d1 * gzz;
        sxy0 += d0 * gxy;    sxy1 += d1 * gxy;
        sxz0 += d0 * gxz;    sxz1 += d1 * gxz;
        syz0 += d0 * gyz;    syz1 += d1 * gyz;
    }

    float tn0 = 3.f*c0*c0 + 2.f*c0*(sxx0+syy0+szz0)
              + sxx0*sxx0 + syy0*syy0 + szz0*szz0
              + 2.f*(sxy0*sxy0 + sxz0*sxz0 + syz0*syz0)
              + 2.f*(ax0*ax0 + ay0*ay0 + az0*az0);
    float tn1 = 3.f*c1*c1 + 2.f*c1*(sxx1+syy1+szz1)
              + sxx1*sxx1 + syy1*syy1 + szz1*szz1
              + 2.f*(sxy1*sxy1 + sxz1*sxz1 + syz1*syz1)
              + 2.f*(ax1*ax1 + ay1*ay1 + az1*az1);

    float s1 = tn0 + tn1, s2 = tn0*tn0 + tn1*tn1;
    #pragma unroll
    for (int d = 1; d < 64; d <<= 1){
        s1 += __shfl_xor(s1, d);
        s2 += __shfl_xor(s2, d);
    }
    float mu  = s1 * (1.f / HID);
    float var = s2 * (1.f / HID) - mu * mu;
    float rs  = rsqrtf(var + LN_EPS);
    float2 g2 = *(const float2*)(ln_g + lane * 2);
    float2 b2 = *(const float2*)(ln_b + lane * 2);
    float ln0 = (tn0 - mu) * rs * g2.x + b2.x;
    float ln1 = (tn1 - mu) * rs * g2.y + b2.y;

    const size_t nrow = (size_t)n * 64 + lane;
    uint_t* LN = (uint_t*)lnb;
    uint_t* AC = (uint_t*)accb;
    LN[nrow] = packbf(ln0, ln1);
    const size_t PS = (size_t)NP * 64;
    AC[0*PS + nrow] = packbf(c0, c1);
    AC[1*PS + nrow] = packbf(ax0, ax1);
    AC[2*PS + nrow] = packbf(ay0, ay1);
    AC[3*PS + nrow] = packbf(az0, az1);
    AC[4*PS + nrow] = packbf(sxx0, sxx1);
    AC[5*PS + nrow] = packbf(syy0, syy1);
    AC[6*PS + nrow] = packbf(szz0, szz1);
    AC[7*PS + nrow] = packbf(sxy0, sxy1);
    AC[8*PS + nrow] = packbf(sxz0, sxz1);
    AC[9*PS + nrow] = packbf(syz0, syz1);
}

// ---------------------------------------------------------------- fused node kernel (r3-proven)
__global__ __launch_bounds__(256) void k_node(
    const bf16_t* __restrict__ lnb, const bf16_t* __restrict__ accb,
    const bf16_t* __restrict__ Ws1b, const float* __restrict__ bs1,
    const bf16_t* __restrict__ Ws2b, const float* __restrict__ bs2,
    const bf16_t* __restrict__ Wtc,
    float* __restrict__ out)
{
    __shared__ __align__(16) bf16_t h1s[16 * 280];
    __shared__ float nrms[16 * 392];

    const int tid = threadIdx.x;
    const int wv = tid >> 6, lane = tid & 63;
    const int col = lane & 15, q = lane >> 4;
    const int n0 = blockIdx.x * 16;

    {
        short8 a1[4];
        #pragma unroll
        for (int k = 0; k < 4; k++)
            a1[k] = *(const short8*)(lnb + (size_t)(n0 + col) * HID + k * 32 + q * 8);
        floatx4 c1[4];
        #pragma unroll
        for (int nt = 0; nt < 4; nt++) c1[nt] = (floatx4)(0.f);
        #pragma unroll
        for (int nt = 0; nt < 4; nt++){
            int cg = wv * 64 + nt * 16 + col;
            #pragma unroll
            for (int k = 0; k < 4; k++){
                short8 b = *(const short8*)(Ws1b + (size_t)cg * HID + k * 32 + q * 8);
                c1[nt] = __builtin_amdgcn_mfma_f32_16x16x32_bf16(a1[k], b, c1[nt], 0, 0, 0);
            }
        }
        #pragma unroll
        for (int nt = 0; nt < 4; nt++){
            int cg = wv * 64 + nt * 16 + col;
            float bias = bs1[cg];
            #pragma unroll
            for (int r = 0; r < 4; r++){
                float v = c1[nt][r] + bias;
                v = v / (1.f + __expf(-v));
                h1s[(q * 4 + r) * 280 + cg] = to_bf16(v);
            }
        }
    }
    __syncthreads();

    {
        short8 a2[8];
        #pragma unroll
        for (int k = 0; k < 8; k++)
            a2[k] = *(const short8*)&h1s[col * 280 + k * 32 + q * 8];
        floatx4 c2[6];
        #pragma unroll
        for (int nt = 0; nt < 6; nt++) c2[nt] = (floatx4)(0.f);
        #pragma unroll
        for (int nt = 0; nt < 6; nt++){
            int cg = wv * 96 + nt * 16 + col;
            #pragma unroll
            for (int k = 0; k < 8; k++){
                short8 b = *(const short8*)(Ws2b + (size_t)cg * 256 + k * 32 + q * 8);
                c2[nt] = __builtin_amdgcn_mfma_f32_16x16x32_bf16(a2[k], b, c2[nt], 0, 0, 0);
            }
        }
        #pragma unroll
        for (int nt = 0; nt < 6; nt++){
            int cg = wv * 96 + nt * 16 + col;
            float bias = bs2[cg];
            #pragma unroll
            for (int r = 0; r < 4; r++){
                float v = c2[nt][r] + bias;
                v = v / (1.f + __expf(-v));
                nrms[(q * 4 + r) * 392 + cg] = v;
            }
        }
    }
    __syncthreads();

    floatx4 cm[10][2];
    #pragma unroll
    for (int p = 0; p < 10; p++){
        #pragma unroll
        for (int nt = 0; nt < 2; nt++) cm[p][nt] = (floatx4)(0.f);
    }
    #pragma unroll
    for (int p = 0; p < 10; p++){
        const bf16_t* ap = accb + (size_t)p * NP * HID + (size_t)(n0 + col) * HID;
        short8 a3[4];
        #pragma unroll
        for (int k = 0; k < 4; k++)
            a3[k] = *(const short8*)(ap + k * 32 + q * 8);
        int tb = (p == 0) ? 0 : ((p < 4) ? 1 : 2);
        #pragma unroll
        for (int nt = 0; nt < 2; nt++){
            int g = wv * 32 + nt * 16 + col;
            const bf16_t* wp = Wtc + tb * 16384 + (size_t)g * HID;
            #pragma unroll
            for (int k = 0; k < 4; k++){
                short8 b = *(const short8*)(wp + k * 32 + q * 8);
                cm[p][nt] = __builtin_amdgcn_mfma_f32_16x16x32_bf16(a3[k], b, cm[p][nt], 0, 0, 0);
            }
        }
    }
    #pragma unroll
    for (int nt = 0; nt < 2; nt++){
        int g = wv * 32 + nt * 16 + col;
        #pragma unroll
        for (int r = 0; r < 4; r++){
            int node = q * 4 + r;
            int n = n0 + node;
            if (n < NN){
                float n0f = nrms[node * 392 + g * 3 + 0];
                float n1f = nrms[node * 392 + g * 3 + 1];
                float n2f = nrms[node * 392 + g * 3 + 2];
                float c   = cm[0][nt][r];
                float ax  = cm[1][nt][r], ay = cm[2][nt][r], az = cm[3][nt][r];
                float sxx = cm[4][nt][r], syy= cm[5][nt][r], szz= cm[6][nt][r];
                float sxy = cm[7][nt][r], sxz= cm[8][nt][r], syz= cm[9][nt][r];
                float* o = out + ((size_t)n * HID + g) * 9;
                o[0] = n0f*c + n2f*sxx;   o[1] = n2f*sxy - n1f*az;  o[2] = n2f*sxz + n1f*ay;
                o[3] = n2f*sxy + n1f*az;  o[4] = n0f*c + n2f*syy;   o[5] = n2f*syz - n1f*ax;
                o[6] = n2f*sxz - n1f*ay;  o[7] = n2f*syz + n1f*ax;  o[8] = n0f*c + n2f*szz;
            }
        }
    }
}

// ---------------------------------------------------------------- launch
extern "C" void kernel_launch(void* const* d_in, const int* in_sizes, int n_in,
                              void* d_out, int out_size, void* d_ws, size_t ws_size,
                              hipStream_t stream)
{
    (void)in_sizes; (void)n_in; (void)out_size; (void)ws_size;
    const int*   z      = (const int*)  d_in[0];
    const int*   ei     = (const int*)  d_in[1];
    const float* ew     = (const float*)d_in[2];
    const float* evn    = (const float*)d_in[3];
    const float* attr   = (const float*)d_in[4];
    const float* emb    = (const float*)d_in[5];
    const float* W_emb2 = (const float*)d_in[6];
    const float* b_emb2 = (const float*)d_in[7];
    const float* Wd1 = (const float*)d_in[8];  const float* bd1 = (const float*)d_in[9];
    const float* Wd2 = (const float*)d_in[10]; const float* bd2 = (const float*)d_in[11];
    const float* Wd3 = (const float*)d_in[12]; const float* bd3 = (const float*)d_in[13];
    const float* Wt1 = (const float*)d_in[14]; const float* Wt2 = (const float*)d_in[15];
    const float* Wt3 = (const float*)d_in[16];
    const float* Ws1 = (const float*)d_in[17]; const float* bs1 = (const float*)d_in[18];
    const float* Ws2 = (const float*)d_in[19]; const float* bs2 = (const float*)d_in[20];
    const float* ln_g = (const float*)d_in[21]; const float* ln_b = (const float*)d_in[22];
    float* out = (float*)d_out;

    char* ws = (char*)d_ws;
    size_t o = 0;
    auto take = [&](size_t b)->size_t{ size_t c = o; o += (b + 255) & ~(size_t)255; return c; };
    size_t f1_o  = take((size_t)NE * HID * 2);
    size_t f2_o  = take((size_t)NE * HID * 2);
    size_t f3_o  = take((size_t)NE * HID * 2);
    size_t acc_o = take((size_t)10 * NP * HID * 2);
    size_t ln_of = take((size_t)NP * HID * 2);
    size_t eL_o  = take((size_t)128 * HID * 4);
    size_t eR_o  = take((size_t)128 * HID * 4);
    size_t cnt_o = take((size_t)NN * 4);
    size_t bkt_o = take((size_t)NN * MAXD * 4);
    size_t met_o = take((size_t)NE * 8);
    size_t ev4_o = take((size_t)NE * 16);
    size_t wc_o  = take((size_t)384 * 64 * 2);
    size_t wt_o  = take((size_t)3 * 128 * 128 * 2);
    size_t w1_o  = take((size_t)256 * 128 * 2);
    size_t w2_o  = take((size_t)384 * 256 * 2);
    size_t bdc_o = take((size_t)384 * 4);

    bf16_t* f1 = (bf16_t*)(ws + f1_o);
    bf16_t* f2 = (bf16_t*)(ws + f2_o);
    bf16_t* f3 = (bf16_t*)(ws + f3_o);
    bf16_t* accb = (bf16_t*)(ws + acc_o);
    bf16_t* lnb  = (bf16_t*)(ws + ln_of);
    float* embL = (float*)(ws + eL_o);
    float* embR = (float*)(ws + eR_o);
    int* cnt    = (int*)(ws + cnt_o);
    int* bucket = (int*)(ws + bkt_o);
    float2* meta2 = (float2*)(ws + met_o);
    float4* evn4  = (float4*)(ws + ev4_o);
    bf16_t* Wcat = (bf16_t*)(ws + wc_o);
    bf16_t* Wtc  = (bf16_t*)(ws + wt_o);
    bf16_t* Ws1b = (bf16_t*)(ws + w1_o);
    bf16_t* Ws2b = (bf16_t*)(ws + w2_o);
    float* bdcat = (float*)(ws + bdc_o);

    hipMemsetAsync(cnt, 0, (size_t)NN * 4, stream);

    k_prep <<<228 + (NE + 255) / 256, 256, 0, stream>>>(
        Wd1, Wd2, Wd3, bd1, bd2, bd3, Wt1, Wt2, Wt3, Ws1, Ws2, W_emb2, emb,
        ei, z, ew, evn, cnt, bucket, meta2, evn4,
        Wcat, Wtc, Ws1b, Ws2b, bdcat, embL, embR);
    k_edge <<<NE / 64, 256, 0, stream>>>(attr, meta2, Wcat, bdcat,
                                         embL, embR, b_emb2, f1, f2, f3);
    k_gather<<<NN / 4, 256, 0, stream>>>(cnt, bucket, evn4, f1, f2, f3,
                                         ln_g, ln_b, accb, lnb);
    k_node <<<(NN + 15) / 16, 256, 0, stream>>>(lnb, accb, Ws1b, bs1, Ws2b, bs2, Wtc, out);
}